// Round 5
// baseline (235.620 us; speedup 1.0000x reference)
//
#include <hip/hip_runtime.h>
#include <stdint.h>

typedef unsigned int   u32;
typedef unsigned short u16;
typedef __bf16 bf16x8 __attribute__((ext_vector_type(8)));
typedef float  f32x4  __attribute__((ext_vector_type(4)));

// ---------------------------------------------------------------------------
// Compile-time DWT analysis matrix Wd[84][64] (db4, reflect, J=3).
// Row order: lo3 (14) | hi1 (35) | hi2 (21) | hi3 (14).
// ---------------------------------------------------------------------------
struct WdT { float v[84][64]; };

constexpr WdT build_wd() {
    WdT W{};
    const float GLc[8] = { 0.23037781330885523f,  0.7148465705525415f,
                           0.6308807679295904f,  -0.02798376941698385f,
                          -0.18703481171888114f,  0.030841381835986965f,
                           0.032883011666982945f,-0.010597401784997278f };
    const float GHc[8] = {-0.010597401784997278f,-0.032883011666982945f,
                           0.030841381835986965f, 0.18703481171888114f,
                          -0.02798376941698385f, -0.6308807679295904f,
                           0.7148465705525415f,  -0.23037781330885523f };
    for (int j = 0; j < 64; ++j) {
        float lo1[35] = {}, lo2[21] = {};
        for (int i = 0; i < 35; ++i) {
            float sl = 0.f, sh = 0.f;
            for (int t = 0; t < 8; ++t) {
                int s = 2*i + t - 6;
                if (s < 0)   s = -s;
                if (s >= 64) s = 126 - s;
                if (s == j) { sl += GLc[t]; sh += GHc[t]; }
            }
            lo1[i] = sl; W.v[14 + i][j] = sh;
        }
        for (int i = 0; i < 21; ++i) {
            float sl = 0.f, sh = 0.f;
            for (int t = 0; t < 8; ++t) {
                int s = 2*i + t - 6;
                if (s < 0)   s = -s;
                if (s >= 36) s = 70 - s;
                if (s < 35) { sl += lo1[s]*GLc[t]; sh += lo1[s]*GHc[t]; }
            }
            lo2[i] = sl; W.v[49 + i][j] = sh;
        }
        for (int i = 0; i < 14; ++i) {
            float sl = 0.f, sh = 0.f;
            for (int t = 0; t < 8; ++t) {
                int s = 2*i + t - 6;
                if (s < 0)   s = -s;
                if (s >= 22) s = 42 - s;
                if (s < 21) { sl += lo2[s]*GLc[t]; sh += lo2[s]*GHc[t]; }
            }
            W.v[i][j] = sl; W.v[70 + i][j] = sh;
        }
    }
    return W;
}

__constant__ WdT WD = build_wd();

__device__ inline u16 f32_bf16(float f) {
    u32 u = __float_as_uint(f);
    u += 0x7fffu + ((u >> 16) & 1u);
    return (u16)(u >> 16);
}
__device__ inline u32 pack2_bf16(float a, float b) {
    u32 ua = __float_as_uint(a); ua += 0x7fffu + ((ua >> 16) & 1u);
    u32 ub = __float_as_uint(b); ub += 0x7fffu + ((ub >> 16) & 1u);
    return (ua >> 16) | (ub & 0xffff0000u);
}

// async 16-byte global -> LDS (fire-and-forget; counted by vmcnt)
typedef const __attribute__((address_space(1))) u32 gas_u32;
typedef __attribute__((address_space(3)))       u32 las_u32;
__device__ inline void gl16(const void* g, void* l) {
    __builtin_amdgcn_global_load_lds((gas_u32*)g, (las_u32*)l, 16, 0, 0);
}

// ---------------------------------------------------------------------------
// Kernel 1: fold conv weights with the constant DWT matrix, emitting bf16
// in MFMA B-fragment order, kb-contiguous:
//   Wf[(((s*128 + kb)*8 + nt)*64 + lane)*8 + j]
//     = Wp[n = nt*16 + (lane&15)][K = kb*32 + (lane>>4)*8 + j]
// ---------------------------------------------------------------------------
__global__ __launch_bounds__(256) void fold_w(const float* __restrict__ cw,
                                              u16* __restrict__ Wf) {
    const int tid = threadIdx.x;
    const int sk  = blockIdx.x;                  // 0..511 = s*128 + n
    const int s   = sk >> 7;
    const int n   = sk & 127;
    const int hw  = tid & 63;
    const int tg  = __builtin_amdgcn_readfirstlane((int)(tid >> 6)); // 0..3
    const int t0  = tg * 16;
    const float* wk = cw + (size_t)sk * (84 * 64);

    float acc[16];
#pragma unroll
    for (int j = 0; j < 16; ++j) acc[j] = 0.f;

#pragma unroll 4
    for (int tau = 0; tau < 84; ++tau) {
        const float wv = wk[tau * 64 + hw];      // coalesced 256 B / wave
#pragma unroll
        for (int j = 0; j < 16; ++j) acc[j] += wv * WD.v[tau][t0 + j]; // s_load
    }

    const int nt  = n >> 4;
    const int fr  = n & 15;
    const int fq  = (hw >> 3) & 3;
    const int jj  = hw & 7;
    const int kbh = hw >> 5;                     // kb = sigma*2 + (hw>>5)
#pragma unroll
    for (int j = 0; j < 16; ++j) {
        const int t = t0 + j;                    // sigma
        const size_t idx =
            ((((size_t)(s * 128 + t * 2 + kbh)) * 8 + nt) * 64 + fq * 16 + fr) * 8 + jj;
        Wf[idx] = f32_bf16(acc[j]);
    }
}

// ---------------------------------------------------------------------------
// Kernel 2: LDS-staged MFMA GEMM, 3-deep pipeline (issue distance 2).
// Grid 128*KQ blocks (XCD-swizzled) = kq x s x mt; 512 thr = 8 waves
// (4 wm x 2 wn), per-wave 16m x 64n.  Block tile 64m x 128n, BK=32,
// NSTEP = 64/KQ... (4096/KQ)/32 steps.  A staged with XOR-swizzled global
// SOURCE (LDS dest linear); B staged linearly (already fragment-ordered).
// Counted vmcnt(4)/(2)/(0) — 2 steps stay in flight across barriers.
// Partials to P[kq]; reduce_k finishes.
// ---------------------------------------------------------------------------
template <int KQ>
__global__ __launch_bounds__(512, 6) void gemm_f(const float* __restrict__ X,
                                                 const u16* __restrict__ Wf,
                                                 float* __restrict__ P) {
    constexpr int NSTEP = (4096 / KQ) / 32;      // 16 for KQ=8, 32 for KQ=4
    __shared__ float As[3][2048];                // [64 m][32 k] fp32, 8 KB x3
    __shared__ u16   Bs[3][4096];                // 8 frags x 1 KB,    8 KB x3

    const int tid  = threadIdx.x;
    const int lane = tid & 63;
    const int w    = tid >> 6;                   // wave 0..7
    const int wm   = w >> 1;                     // 0..3 (16-row band)
    const int wn   = w & 1;                      // 0..1 (64-col half)
    const int fr   = lane & 15;
    const int fq   = lane >> 4;

    const int bid  = blockIdx.x;                 // grid = 128*KQ, %8 == 0
    const int wg   = (bid & 7) * (16 * KQ) + (bid >> 3);  // XCD-chunked
    const int mt   = wg & 31;
    const int s    = (wg >> 5) & 3;
    const int kq   = wg >> 7;                    // 0..KQ-1

    // ---- staging addresses -------------------------------------------------
    // A: thread t stages LDS linear byte t*16 -> m = t>>3, row-byte (t&7)*16,
    //    global source byte XOR-swizzled by ((m&7)<<4).
    const int am   = tid >> 3;                   // 0..63
    const int ab   = ((tid & 7) * 16) ^ ((am & 7) << 4);
    const float* xa = X + (size_t)(mt * 64 + am) * 16384 + s * 4096
                        + (size_t)kq * (4096 / KQ) + (ab >> 2);
    // B: thread t stages byte t*16 of the step's 8 KB chunk (linear).
    const char* wb0 = (const char*)Wf + ((size_t)(s * 128 + kq * NSTEP) << 13)
                        + (size_t)tid * 16;

    f32x4 acc[4];
#pragma unroll
    for (int ni = 0; ni < 4; ++ni) acc[ni] = (f32x4){0.f, 0.f, 0.f, 0.f};

#define STAGE(buf, step)                                                       \
    do {                                                                       \
        gl16(xa + (size_t)(step) * 32, (char*)&As[buf][0] + tid * 16);         \
        gl16(wb0 + ((size_t)(step) << 13), (char*)&Bs[buf][0] + tid * 16);     \
    } while (0)

    STAGE(0, 0);
    STAGE(1, 1);

#pragma unroll
    for (int step = 0; step < NSTEP; ++step) {
        const int buf = step % 3;
        if (step + 2 < NSTEP) {
            STAGE((step + 2) % 3, step + 2);
            asm volatile("s_waitcnt vmcnt(4)" ::: "memory"); // step landed; 2 in flight
        } else if (step + 2 == NSTEP) {
            asm volatile("s_waitcnt vmcnt(2)" ::: "memory");
        } else {
            asm volatile("s_waitcnt vmcnt(0)" ::: "memory");
        }
        __builtin_amdgcn_s_barrier();

        const float* Ab = &As[buf][0];
        const u16*   Bb = &Bs[buf][0];
        bf16x8 bfr[4];
#pragma unroll
        for (int ni = 0; ni < 4; ++ni)
            bfr[ni] = *reinterpret_cast<const bf16x8*>(
                Bb + ((wn * 4 + ni) * 64 + lane) * 8);

        const int m   = wm * 16 + fr;
        const int swz = (fr & 7) << 4;
        const int b0  = (fq * 32) ^ swz;
        const int b1  = (fq * 32 + 16) ^ swz;
        const f32x4 r0 = *reinterpret_cast<const f32x4*>(Ab + m * 32 + (b0 >> 2));
        const f32x4 r1 = *reinterpret_cast<const f32x4*>(Ab + m * 32 + (b1 >> 2));
        union { u32 u[4]; bf16x8 v; } av;
        av.u[0] = pack2_bf16(r0.x, r0.y); av.u[1] = pack2_bf16(r0.z, r0.w);
        av.u[2] = pack2_bf16(r1.x, r1.y); av.u[3] = pack2_bf16(r1.z, r1.w);
#pragma unroll
        for (int ni = 0; ni < 4; ++ni)
            acc[ni] = __builtin_amdgcn_mfma_f32_16x16x32_bf16(av.v, bfr[ni],
                                                              acc[ni], 0, 0, 0);

        asm volatile("s_waitcnt lgkmcnt(0)" ::: "memory");   // my ds_reads done
        __builtin_amdgcn_s_barrier();                        // safe to overwrite
    }
#undef STAGE

    // partial write: P[kq][mt*64 + wm*16 + fq*4 + r][s*128 + wn*64 + ni*16 + fr]
    float* pg = P + (size_t)kq * (2048 * 512)
                  + (size_t)(mt * 64 + wm * 16) * 512 + s * 128 + wn * 64 + fr;
#pragma unroll
    for (int ni = 0; ni < 4; ++ni)
#pragma unroll
        for (int r = 0; r < 4; ++r)
            pg[(size_t)(fq * 4 + r) * 512 + ni * 16] = acc[ni][r];
}

// ---------------------------------------------------------------------------
// Kernel 3: reduce K-slices, add bias, leaky-ReLU.
// ---------------------------------------------------------------------------
__global__ __launch_bounds__(256) void reduce_k(const float* __restrict__ P,
                                                const float* __restrict__ bias,
                                                float* __restrict__ out, int nks) {
    const int t = blockIdx.x * 256 + threadIdx.x;     // 0..262143
    const size_t base = (size_t)t * 4;
    f32x4 sum = {0.f, 0.f, 0.f, 0.f};
    for (int k = 0; k < nks; ++k)
        sum += *reinterpret_cast<const f32x4*>(P + (size_t)k * (2048 * 512) + base);
    const f32x4 b = *reinterpret_cast<const f32x4*>(bias + (base & 511));
    f32x4 o = sum + b;
    o.x = o.x > 0.f ? o.x : 0.01f * o.x;
    o.y = o.y > 0.f ? o.y : 0.01f * o.y;
    o.z = o.z > 0.f ? o.z : 0.01f * o.z;
    o.w = o.w > 0.f ? o.w : 0.01f * o.w;
    __builtin_nontemporal_store(o, reinterpret_cast<f32x4*>(out + base));
}

// ---------------------------------------------------------------------------
extern "C" void kernel_launch(void* const* d_in, const int* in_sizes, int n_in,
                              void* d_out, int out_size, void* d_ws, size_t ws_size,
                              hipStream_t stream) {
    const float* x  = (const float*)d_in[0];   // [2048,1,256,8,8] fp32
    const float* cw = (const float*)d_in[1];   // [4,128,84,8,8]   fp32
    const float* cb = (const float*)d_in[2];   // [4,128]          fp32
    float* out = (float*)d_out;                // [2048,512]       fp32

    u16*   Wf = (u16*)d_ws;                              // 4 MiB
    float* P  = (float*)((char*)d_ws + (4u << 20));      // KQ * 4 MiB partials

    const size_t MN = (size_t)2048 * 512 * 4;
    fold_w<<<512, 256, 0, stream>>>(cw, Wf);
    if (ws_size >= (4u << 20) + 8 * MN) {
        gemm_f<8><<<1024, 512, 0, stream>>>(x, Wf, P);
        reduce_k<<<1024, 256, 0, stream>>>(P, cb, out, 8);
    } else {
        gemm_f<4><<<512, 512, 0, stream>>>(x, Wf, P);
        reduce_k<<<1024, 256, 0, stream>>>(P, cb, out, 4);
    }
}

// Round 6
// 231.380 us; speedup vs baseline: 1.0183x; 1.0183x over previous
//
#include <hip/hip_runtime.h>
#include <stdint.h>

typedef unsigned int   u32;
typedef unsigned short u16;
typedef __bf16 bf16x8 __attribute__((ext_vector_type(8)));
typedef float  f32x4  __attribute__((ext_vector_type(4)));

// ---------------------------------------------------------------------------
// Compile-time DWT analysis matrix Wd[84][64] (db4, reflect, J=3).
// Row order: lo3 (14) | hi1 (35) | hi2 (21) | hi3 (14).
// ---------------------------------------------------------------------------
struct WdT { float v[84][64]; };

constexpr WdT build_wd() {
    WdT W{};
    const float GLc[8] = { 0.23037781330885523f,  0.7148465705525415f,
                           0.6308807679295904f,  -0.02798376941698385f,
                          -0.18703481171888114f,  0.030841381835986965f,
                           0.032883011666982945f,-0.010597401784997278f };
    const float GHc[8] = {-0.010597401784997278f,-0.032883011666982945f,
                           0.030841381835986965f, 0.18703481171888114f,
                          -0.02798376941698385f, -0.6308807679295904f,
                           0.7148465705525415f,  -0.23037781330885523f };
    for (int j = 0; j < 64; ++j) {
        float lo1[35] = {}, lo2[21] = {};
        for (int i = 0; i < 35; ++i) {
            float sl = 0.f, sh = 0.f;
            for (int t = 0; t < 8; ++t) {
                int s = 2*i + t - 6;
                if (s < 0)   s = -s;
                if (s >= 64) s = 126 - s;
                if (s == j) { sl += GLc[t]; sh += GHc[t]; }
            }
            lo1[i] = sl; W.v[14 + i][j] = sh;
        }
        for (int i = 0; i < 21; ++i) {
            float sl = 0.f, sh = 0.f;
            for (int t = 0; t < 8; ++t) {
                int s = 2*i + t - 6;
                if (s < 0)   s = -s;
                if (s >= 36) s = 70 - s;
                if (s < 35) { sl += lo1[s]*GLc[t]; sh += lo1[s]*GHc[t]; }
            }
            lo2[i] = sl; W.v[49 + i][j] = sh;
        }
        for (int i = 0; i < 14; ++i) {
            float sl = 0.f, sh = 0.f;
            for (int t = 0; t < 8; ++t) {
                int s = 2*i + t - 6;
                if (s < 0)   s = -s;
                if (s >= 22) s = 42 - s;
                if (s < 21) { sl += lo2[s]*GLc[t]; sh += lo2[s]*GHc[t]; }
            }
            W.v[i][j] = sl; W.v[70 + i][j] = sh;
        }
    }
    return W;
}

__constant__ WdT WD = build_wd();

__device__ inline u16 f32_bf16(float f) {
    u32 u = __float_as_uint(f);
    u += 0x7fffu + ((u >> 16) & 1u);
    return (u16)(u >> 16);
}
__device__ inline u32 pack2_bf16(float a, float b) {
    u32 ua = __float_as_uint(a); ua += 0x7fffu + ((ua >> 16) & 1u);
    u32 ub = __float_as_uint(b); ub += 0x7fffu + ((ub >> 16) & 1u);
    return (ua >> 16) | (ub & 0xffff0000u);
}

// async 16-byte global -> LDS (fire-and-forget; counted by vmcnt)
typedef const __attribute__((address_space(1))) u32 gas_u32;
typedef __attribute__((address_space(3)))       u32 las_u32;
__device__ inline void gl16(const void* g, void* l) {
    __builtin_amdgcn_global_load_lds((gas_u32*)g, (las_u32*)l, 16, 0, 0);
}

// ---------------------------------------------------------------------------
// Kernel 1: fold conv weights with the constant DWT matrix, emitting bf16
// in MFMA B-fragment order, kb-contiguous:
//   Wf[(((s*128 + kb)*8 + nt)*64 + lane)*8 + j]
//     = Wp[n = nt*16 + (lane&15)][K = kb*32 + (lane>>4)*8 + j]
// ---------------------------------------------------------------------------
__global__ __launch_bounds__(256) void fold_w(const float* __restrict__ cw,
                                              u16* __restrict__ Wf) {
    const int tid = threadIdx.x;
    const int sk  = blockIdx.x;                  // 0..511 = s*128 + n
    const int s   = sk >> 7;
    const int n   = sk & 127;
    const int hw  = tid & 63;
    const int tg  = __builtin_amdgcn_readfirstlane((int)(tid >> 6)); // 0..3
    const int t0  = tg * 16;
    const float* wk = cw + (size_t)sk * (84 * 64);

    float acc[16];
#pragma unroll
    for (int j = 0; j < 16; ++j) acc[j] = 0.f;

#pragma unroll 4
    for (int tau = 0; tau < 84; ++tau) {
        const float wv = wk[tau * 64 + hw];      // coalesced 256 B / wave
#pragma unroll
        for (int j = 0; j < 16; ++j) acc[j] += wv * WD.v[tau][t0 + j]; // s_load
    }

    const int nt  = n >> 4;
    const int fr  = n & 15;
    const int fq  = (hw >> 3) & 3;
    const int jj  = hw & 7;
    const int kbh = hw >> 5;                     // kb = sigma*2 + (hw>>5)
#pragma unroll
    for (int j = 0; j < 16; ++j) {
        const int t = t0 + j;                    // sigma
        const size_t idx =
            ((((size_t)(s * 128 + t * 2 + kbh)) * 8 + nt) * 64 + fq * 16 + fr) * 8 + jj;
        Wf[idx] = f32_bf16(acc[j]);
    }
}

// ---------------------------------------------------------------------------
// Kernel 2: full-K LDS-staged MFMA GEMM, bias + leakyReLU fused.
// Grid 512 blocks (XCD-swizzled) = s x mt; 512 thr = 8 waves, wave w owns
// the 16m x 16n output tile (n-block w) over ALL K=4096 — no K reduction.
// Block tile 16m x 128n, BK=128 per stage, 32 stages, 2-deep pipeline.
// A: 16 rows x 512 B CONTIGUOUS per stage, successive stages continue
// within each row -> DRAM-page-friendly streaming (fixes the 128B-random
// pattern that capped R4/R5 at ~2.7 TB/s).  XOR-swizzled source, linear
// LDS dest, swizzled read.  B: 32 KB contiguous per stage from L2-resident
// Wf.  Counted vmcnt(5) steady state.
// ---------------------------------------------------------------------------
__global__ __launch_bounds__(512, 4) void gemm_f(const float* __restrict__ X,
                                                 const u16* __restrict__ Wf,
                                                 const float* __restrict__ bias,
                                                 float* __restrict__ out) {
    __shared__ float As[2][2048];                // [16 m][128 k] fp32, 8 KB x2
    __shared__ u16   Bs[2][16384];               // 4 kb x 8 frag x 1KB, 32 KB x2

    const int tid  = threadIdx.x;
    const int lane = tid & 63;
    const int w    = tid >> 6;                   // n-block 0..7
    const int fr   = lane & 15;
    const int fq   = lane >> 4;                  // 0..3

    const int bid  = blockIdx.x;                 // 512 % 8 == 0 -> bijective
    const int wg   = ((bid & 7) << 6) + (bid >> 3);  // XCD-chunked swizzle
    const int mt   = wg & 127;                   // m-tile (16 rows)
    const int s    = wg >> 7;                    // subwindow

    // ---- staging addresses -------------------------------------------------
    // A: thread t -> LDS byte t*16: m = t>>5, col-byte (t&31)*16 in a 512B row;
    //    global source col-byte XOR-swizzled by ((m&7)<<4) (within 128B group).
    const int am   = tid >> 5;                   // 0..15
    const int acb  = ((tid & 31) * 16) ^ ((am & 7) << 4);
    const float* xa = X + (size_t)(mt * 16 + am) * 16384 + s * 4096 + (acb >> 2);
    // B: thread t stages bytes t*16 + j*8192 of the stage's 32 KB chunk.
    const char* wb0 = (const char*)Wf + ((size_t)s << 20) + (size_t)tid * 16;

    f32x4 acc = (f32x4){0.f, 0.f, 0.f, 0.f};

#define STAGE(buf, st)                                                         \
    do {                                                                       \
        gl16(xa + (size_t)(st) * 128, (char*)&As[buf][0] + tid * 16);          \
        const char* gb = wb0 + ((size_t)(st) << 15);                           \
        char*       lb = (char*)&Bs[buf][0] + tid * 16;                        \
        gl16(gb,         lb);                                                  \
        gl16(gb +  8192, lb +  8192);                                          \
        gl16(gb + 16384, lb + 16384);                                          \
        gl16(gb + 24576, lb + 24576);                                          \
    } while (0)

    STAGE(0, 0);

    const int swz = (fr & 7) << 4;
#pragma unroll 2
    for (int step = 0; step < 32; ++step) {
        const int buf = step & 1;
        if (step + 1 < 32) {
            STAGE(buf ^ 1, step + 1);
            asm volatile("s_waitcnt vmcnt(5)" ::: "memory"); // stage landed; next in flight
        } else {
            asm volatile("s_waitcnt vmcnt(0)" ::: "memory");
        }
        __builtin_amdgcn_s_barrier();

        const char* Ab = (const char*)&As[buf][0];
        const u16*  Bb = &Bs[buf][0];
#pragma unroll
        for (int sub = 0; sub < 4; ++sub) {
            const bf16x8 bf = *reinterpret_cast<const bf16x8*>(
                Bb + ((sub * 8 + w) * 64 + lane) * 8);
            const int b0 = (sub * 128 + fq * 32) ^ swz;
            const int b1 = (sub * 128 + fq * 32 + 16) ^ swz;
            const f32x4 r0 = *reinterpret_cast<const f32x4*>(Ab + fr * 512 + b0);
            const f32x4 r1 = *reinterpret_cast<const f32x4*>(Ab + fr * 512 + b1);
            union { u32 u[4]; bf16x8 v; } av;
            av.u[0] = pack2_bf16(r0.x, r0.y); av.u[1] = pack2_bf16(r0.z, r0.w);
            av.u[2] = pack2_bf16(r1.x, r1.y); av.u[3] = pack2_bf16(r1.z, r1.w);
            acc = __builtin_amdgcn_mfma_f32_16x16x32_bf16(av.v, bf, acc, 0, 0, 0);
        }

        asm volatile("s_waitcnt lgkmcnt(0)" ::: "memory");   // my ds_reads done
        __builtin_amdgcn_s_barrier();                        // safe to overwrite
    }
#undef STAGE

    // epilogue: C[m = fq*4+r][n = fr] of wave's 16x16 tile; bias + leakyReLU
    const float bb = bias[s * 128 + w * 16 + fr];
    float* og = out + (size_t)(mt * 16) * 512 + s * 128 + w * 16 + fr;
#pragma unroll
    for (int r = 0; r < 4; ++r) {
        float v = acc[r] + bb;
        v = v > 0.f ? v : 0.01f * v;
        og[(size_t)(fq * 4 + r) * 512] = v;
    }
}

// ---------------------------------------------------------------------------
extern "C" void kernel_launch(void* const* d_in, const int* in_sizes, int n_in,
                              void* d_out, int out_size, void* d_ws, size_t ws_size,
                              hipStream_t stream) {
    const float* x  = (const float*)d_in[0];   // [2048,1,256,8,8] fp32
    const float* cw = (const float*)d_in[1];   // [4,128,84,8,8]   fp32
    const float* cb = (const float*)d_in[2];   // [4,128]          fp32
    float* out = (float*)d_out;                // [2048,512]       fp32

    u16* Wf = (u16*)d_ws;                      // 4 MiB, B-fragment order

    fold_w<<<512, 256, 0, stream>>>(cw, Wf);
    gemm_f<<<512, 512, 0, stream>>>(x, Wf, cb, out);
}